// Round 12
// baseline (190.746 us; speedup 1.0000x reference)
//
#include <hip/hip_runtime.h>

#define B_  2
#define T_  2048
#define C_  1024
#define H_  16
#define HS_ 64
#define M_  4096   // B_*T_
#define N3_ 3072

typedef __bf16 bf16;
typedef bf16  bf16x4 __attribute__((ext_vector_type(4)));
typedef bf16  bf16x8 __attribute__((ext_vector_type(8)));
typedef float f32x4  __attribute__((ext_vector_type(4)));

__device__ __forceinline__ bf16 f2bf(float x) {
  union { float f; unsigned u; } v; v.f = x;
  unsigned r = (v.u + 0x7FFFu + ((v.u >> 16) & 1u)) >> 16;
  union { unsigned short s; bf16 b; } o; o.s = (unsigned short)r;
  return o.b;
}

// pack two fp32 -> two bf16 (round via +0x8000), lane-local, ~3 VALU ops
__device__ __forceinline__ unsigned pk2bf(float lo, float hi) {
  union { float f; unsigned u; } a, b;
  a.f = lo; b.f = hi;
  return ((a.u + 0x8000u) >> 16) | ((b.u + 0x8000u) & 0xFFFF0000u);
}

#define GLB(p) ((const __attribute__((address_space(1))) void*)(p))
#define LDSP(p) ((__attribute__((address_space(3))) void*)(p))
#define VMCNT(n) asm volatile("s_waitcnt vmcnt(" #n ")" ::: "memory")
#define BAR() asm volatile("s_barrier" ::: "memory")

// ---------------- fused prep: cast x, transpose W_attn/W_proj, transpose W_l1/l2 ----------------
//   [0,4096)            cast_x  (f32x4 -> bf16x4)
//   [4096, 4096+3072)   transpose_cast W_attn [1024][3072] -> WaT [3072][1024]
//   [7168, 7168+1024)   transpose_cast W_proj [1024][1024] -> WpT
//   [8192, 8192+32)     cast_wl (W_l1/W_l2 64x64 transpose)
__global__ __launch_bounds__(256)
void prep_kernel(const float* __restrict__ x, bf16* __restrict__ Xbf,
                 const float* __restrict__ W_attn, bf16* __restrict__ WaT,
                 const float* __restrict__ W_proj, bf16* __restrict__ WpT,
                 const float* __restrict__ W1, const float* __restrict__ W2,
                 bf16* __restrict__ W1T, bf16* __restrict__ W2T) {
  __shared__ float tile[32][33];
  int bid = blockIdx.x;
  const int tid = threadIdx.x;
  if (bid < 4096) {                       // ---- cast_x
    const int i = bid * 256 + tid;        // n4 = 4096*256 exactly
    float4 v = ((const float4*)x)[i];
    bf16 o[4] = {f2bf(v.x), f2bf(v.y), f2bf(v.z), f2bf(v.w)};
    *(uint2*)(Xbf + (size_t)i * 4) = *(uint2*)o;
    return;
  }
  bid -= 4096;
  if (bid < 3072 + 1024) {                // ---- transposes (32x32 tile, 256 thr as 32x8)
    const float* in; bf16* out; int R, Cc, bx, by;
    if (bid < 3072) { in = W_attn; out = WaT; R = C_; Cc = N3_; bx = bid % 96; by = bid / 96; }
    else { const int b2 = bid - 3072; in = W_proj; out = WpT; R = C_; Cc = C_; bx = b2 & 31; by = b2 >> 5; }
    const int c0 = bx * 32, r0 = by * 32;
    const int tx = tid & 31, ty = tid >> 5;
    #pragma unroll
    for (int i = ty; i < 32; i += 8)
      tile[i][tx] = in[(size_t)(r0 + i) * Cc + c0 + tx];
    __syncthreads();
    #pragma unroll
    for (int i = ty; i < 32; i += 8)
      out[(size_t)(c0 + i) * R + r0 + tx] = f2bf(tile[tx][i]);
    return;
  }
  bid -= 4096;                            // ---- cast_wl: 32 blocks
  const int t2 = bid * 256 + tid;         // 8192 total
  const int m = t2 >> 12, e = t2 & 4095;
  const int j = e >> 6, d = e & 63;
  const float* src = m ? W2 : W1;
  bf16* dst = m ? W2T : W1T;
  dst[e] = f2bf(src[d * 64 + j]);
}

// ------------- 128x128 4-wave pipelined QKV GEMM — 1 barrier + 1 vmcnt per K-tile -------------
// Qo/Ko/Vo = A[4096,1024] @ WaT[3072,1024]^T + bias, split bf16 epilogue.
// R12: 256²-tile version ran 192 blocks on 256 CUs (64 CUs idle, 1 block/CU, no overlap
// across its 17 barrier drains). 128² tiles -> 768 blocks, 64KB LDS -> 2 blocks/CU
// co-resident over 3 rounds: full CU coverage + cross-block barrier-drain overlap.
// Same proven ledger: VMCNT(0) -> BAR -> stage ALL of t+1 (8 gload_lds) -> 32 MFMA.
__global__ __launch_bounds__(256, 2)
void gemm128_qkv(const bf16* __restrict__ A, const bf16* __restrict__ Bt,
                 const float* __restrict__ bias,
                 bf16* __restrict__ Qo, bf16* __restrict__ Ko, bf16* __restrict__ Vo) {
  constexpr int K = C_;          // 1024
  constexpr int NT = K / 64;     // 16 K-tiles
  __shared__ __attribute__((aligned(16))) char SM[65536];  // [slot][A 16KB | B 16KB]
  const int tid = threadIdx.x;
  const int lane = tid & 63, w = tid >> 6;
  const int l = lane & 15, quad = lane >> 4;
  const int lsw = l & 7;
  const int wm = (w >> 1) * 64, wn = (w & 1) * 64;   // 2x2 wave grid, wave tile 64x64

  // XCD-chunked swizzle: 768 blocks, 96/XCD; by = lin/24 (0..31), bx = lin%24 (0..23)
  const int bid = blockIdx.x;
  const int lin = (bid & 7) * 96 + (bid >> 3);
  const int by = lin / 24, bx = lin - by * 24;
  const int m0 = by * 128, n0 = bx * 128;

  const int srow = tid >> 3;                              // 0..31
  const int scol = ((tid & 7) ^ ((tid >> 3) & 7)) * 8;    // pre-swizzled source col
  const bf16* Asrc = A + (size_t)(m0 + srow) * K + scol;
  const bf16* Bsrc = Bt + (size_t)(n0 + srow) * K + scol;
  char* dstb = SM + tid * 16;

  auto stg_tile = [&](int slot, int t) {    // all 8 loads for one K-tile (A 16KB + B 16KB)
    #pragma unroll
    for (int h = 0; h < 2; ++h)
      #pragma unroll
      for (int i = 0; i < 2; ++i)
        __builtin_amdgcn_global_load_lds(
            GLB(Asrc + (size_t)(h * 64 + i * 32) * K + t * 64),
            LDSP(dstb + slot * 32768 + h * 8192 + i * 4096), 16, 0, 0);
    #pragma unroll
    for (int h = 0; h < 2; ++h)
      #pragma unroll
      for (int i = 0; i < 2; ++i)
        __builtin_amdgcn_global_load_lds(
            GLB(Bsrc + (size_t)(h * 64 + i * 32) * K + t * 64),
            LDSP(dstb + slot * 32768 + 16384 + h * 8192 + i * 4096), 16, 0, 0);
  };
  auto ldsA = [&](int slot, int mi, int kk) {
    return *(const bf16x8*)(SM + slot * 32768 + (wm + mi * 16 + l) * 128 +
                            (((kk * 4 + quad) ^ lsw) * 16));
  };
  auto ldsB = [&](int slot, int ni, int kk) {
    return *(const bf16x8*)(SM + slot * 32768 + 16384 + (wn + ni * 16 + l) * 128 +
                            (((kk * 4 + quad) ^ lsw) * 16));
  };

  f32x4 acc[4][4];
  #pragma unroll
  for (int mi = 0; mi < 4; ++mi)
    #pragma unroll
    for (int ni = 0; ni < 4; ++ni)
      acc[mi][ni] = (f32x4){0.f, 0.f, 0.f, 0.f};

  bf16x8 af[4][2];
  auto phase_mfma = [&](bf16x8 (&bp)[2][2], int nbase) {
    __builtin_amdgcn_s_setprio(1);
    #pragma unroll
    for (int mi = 0; mi < 4; ++mi)
      #pragma unroll
      for (int nj = 0; nj < 2; ++nj) {
        acc[mi][nbase + nj] = __builtin_amdgcn_mfma_f32_16x16x32_bf16(
            af[mi][0], bp[nj][0], acc[mi][nbase + nj], 0, 0, 0);
        acc[mi][nbase + nj] = __builtin_amdgcn_mfma_f32_16x16x32_bf16(
            af[mi][1], bp[nj][1], acc[mi][nbase + nj], 0, 0, 0);
      }
    __builtin_amdgcn_s_setprio(0);
  };

  stg_tile(0, 0);

  for (int t = 0; t < NT; ++t) {
    const int st = t & 1, ns = st ^ 1;
    VMCNT(0);   // t's loads done (issued a full tile ago)
    BAR();      // slot st visible; all waves done reading slot ns (tile t-1)
    if (t + 1 < NT) stg_tile(ns, t + 1);

    #pragma unroll
    for (int mi = 0; mi < 4; ++mi) {
      af[mi][0] = ldsA(st, mi, 0);
      af[mi][1] = ldsA(st, mi, 1);
    }
    #pragma unroll
    for (int g = 0; g < 2; ++g) {
      bf16x8 bp[2][2];
      #pragma unroll
      for (int nj = 0; nj < 2; ++nj) {
        bp[nj][0] = ldsB(st, g * 2 + nj, 0);
        bp[nj][1] = ldsB(st, g * 2 + nj, 1);
      }
      phase_mfma(bp, g * 2);
    }
  }

  // epilogue: segment (Q/K/V) is block-uniform since 128 | 1024
  const int seg = n0 >> 10;
  const int ncol0 = (n0 & 1023) + wn;
  #pragma unroll
  for (int mi = 0; mi < 4; ++mi) {
    #pragma unroll
    for (int ni = 0; ni < 4; ++ni) {
      const float bb = bias[n0 + wn + ni * 16 + l];
      #pragma unroll
      for (int r = 0; r < 4; ++r) {
        const int row = m0 + wm + mi * 16 + quad * 4 + r;
        const float v = acc[mi][ni][r] + bb;
        const size_t idx = (size_t)row * C_ + ncol0 + ni * 16 + l;
        if (seg == 0)      Qo[idx] = f2bf(v * 0.1803368801f);
        else if (seg == 1) Ko[idx] = f2bf(v);
        else               Vo[idx] = f2bf(v);
      }
    }
  }
}

// ------------- 128x128 4-wave pipelined proj GEMM — same 1-barrier/tile ledger -------------
// Fo[4096][1024] = A[4096,1024] @ Bt[1024,1024]^T + bias (fp32 out).
// Grid 256 blocks. 2 LDS slots x (A 16KB + B 16KB) = 64KB -> 2 blocks/CU possible.
__global__ __launch_bounds__(256, 2)
void gemm128_proj(const bf16* __restrict__ A, const bf16* __restrict__ Bt,
                  const float* __restrict__ bias, float* __restrict__ Fo) {
  constexpr int K = C_;          // 1024
  constexpr int NT = K / 64;     // 16 K-tiles
  __shared__ __attribute__((aligned(16))) char SM[65536];  // [slot][A 16KB | B 16KB]
  const int tid = threadIdx.x;
  const int lane = tid & 63, w = tid >> 6;
  const int l = lane & 15, quad = lane >> 4;
  const int lsw = l & 7;
  const int wm = (w >> 1) * 64, wn = (w & 1) * 64;   // 2x2 wave grid, wave tile 64x64

  // XCD-chunked swizzle: 256 blocks, 32/XCD
  const int bid = blockIdx.x;
  const int lin = (bid & 7) * 32 + (bid >> 3);
  const int by = lin >> 3, bx = lin & 7;             // 32 x 8
  const int m0 = by * 128, n0 = bx * 128;

  const int srow = tid >> 3;                              // 0..31
  const int scol = ((tid & 7) ^ ((tid >> 3) & 7)) * 8;    // pre-swizzled source col
  const bf16* Asrc = A + (size_t)(m0 + srow) * K + scol;
  const bf16* Bsrc = Bt + (size_t)(n0 + srow) * K + scol;
  char* dstb = SM + tid * 16;

  auto stg_tile = [&](int slot, int t) {    // all 8 loads for one K-tile (A 16KB + B 16KB)
    #pragma unroll
    for (int h = 0; h < 2; ++h)
      #pragma unroll
      for (int i = 0; i < 2; ++i)
        __builtin_amdgcn_global_load_lds(
            GLB(Asrc + (size_t)(h * 64 + i * 32) * K + t * 64),
            LDSP(dstb + slot * 32768 + h * 8192 + i * 4096), 16, 0, 0);
    #pragma unroll
    for (int h = 0; h < 2; ++h)
      #pragma unroll
      for (int i = 0; i < 2; ++i)
        __builtin_amdgcn_global_load_lds(
            GLB(Bsrc + (size_t)(h * 64 + i * 32) * K + t * 64),
            LDSP(dstb + slot * 32768 + 16384 + h * 8192 + i * 4096), 16, 0, 0);
  };
  auto ldsA = [&](int slot, int mi, int kk) {
    return *(const bf16x8*)(SM + slot * 32768 + (wm + mi * 16 + l) * 128 +
                            (((kk * 4 + quad) ^ lsw) * 16));
  };
  auto ldsB = [&](int slot, int ni, int kk) {
    return *(const bf16x8*)(SM + slot * 32768 + 16384 + (wn + ni * 16 + l) * 128 +
                            (((kk * 4 + quad) ^ lsw) * 16));
  };

  f32x4 acc[4][4];
  #pragma unroll
  for (int mi = 0; mi < 4; ++mi)
    #pragma unroll
    for (int ni = 0; ni < 4; ++ni)
      acc[mi][ni] = (f32x4){0.f, 0.f, 0.f, 0.f};

  bf16x8 af[4][2];
  auto phase_mfma = [&](bf16x8 (&bp)[2][2], int nbase) {
    __builtin_amdgcn_s_setprio(1);
    #pragma unroll
    for (int mi = 0; mi < 4; ++mi)
      #pragma unroll
      for (int nj = 0; nj < 2; ++nj) {
        acc[mi][nbase + nj] = __builtin_amdgcn_mfma_f32_16x16x32_bf16(
            af[mi][0], bp[nj][0], acc[mi][nbase + nj], 0, 0, 0);
        acc[mi][nbase + nj] = __builtin_amdgcn_mfma_f32_16x16x32_bf16(
            af[mi][1], bp[nj][1], acc[mi][nbase + nj], 0, 0, 0);
      }
    __builtin_amdgcn_s_setprio(0);
  };

  stg_tile(0, 0);

  for (int t = 0; t < NT; ++t) {
    const int st = t & 1, ns = st ^ 1;
    VMCNT(0);
    BAR();
    if (t + 1 < NT) stg_tile(ns, t + 1);

    #pragma unroll
    for (int mi = 0; mi < 4; ++mi) {
      af[mi][0] = ldsA(st, mi, 0);
      af[mi][1] = ldsA(st, mi, 1);
    }
    #pragma unroll
    for (int g = 0; g < 2; ++g) {
      bf16x8 bp[2][2];
      #pragma unroll
      for (int nj = 0; nj < 2; ++nj) {
        bp[nj][0] = ldsB(st, g * 2 + nj, 0);
        bp[nj][1] = ldsB(st, g * 2 + nj, 1);
      }
      phase_mfma(bp, g * 2);
    }
  }

  #pragma unroll
  for (int mi = 0; mi < 4; ++mi) {
    #pragma unroll
    for (int ni = 0; ni < 4; ++ni) {
      const float bb = bias[n0 + wn + ni * 16 + l];
      #pragma unroll
      for (int r = 0; r < 4; ++r) {
        const int row = m0 + wm + mi * 16 + quad * 4 + r;
        Fo[(size_t)row * C_ + n0 + wn + ni * 16 + l] = acc[mi][ni][r] + bb;
      }
    }
  }
}

// ---------------- v-gating via MFMA: gv = (v + v@W1 + b1) * sigmoid(v@W2 + b2) ----------------
// Writes GVt [b][h][j][t'] with INTERLEAVED key order within each 32-t block.
__global__ __launch_bounds__(256)
void gate_kernel(const bf16* __restrict__ V, const bf16* __restrict__ W1T,
                 const float* __restrict__ b1, const bf16* __restrict__ W2T,
                 const float* __restrict__ b2, bf16* __restrict__ GVt) {
  __shared__ bf16 Vs[128 * 64];
  __shared__ bf16 W1s[64 * 64];
  __shared__ bf16 W2s[64 * 64];
  const int tid = threadIdx.x, w = tid >> 6, lane = tid & 63;
  const int l = lane & 15, quad = lane >> 4;
  const int bh = blockIdx.y;
  const int t0 = blockIdx.x * 128;
  const int b = bh >> 4, h = bh & 15;
  const int bT = b * T_, hc = h * 64, bh64 = bh * 64;

  #pragma unroll
  for (int i = 0; i < 4; ++i) {
    const int p = tid + i * 256;
    const int row = p >> 3, cc = (p & 7) ^ (row & 7);
    const bf16* gv = V + (size_t)(bT + t0 + row) * C_ + hc + cc * 8;
    __builtin_amdgcn_global_load_lds(GLB(gv), LDSP((char*)Vs + p * 16), 16, 0, 0);
  }
  #pragma unroll
  for (int i = 0; i < 2; ++i) {
    const int p = tid + i * 256;
    const int row = p >> 3, cc = (p & 7) ^ (row & 7);
    __builtin_amdgcn_global_load_lds(GLB(W1T + row * 64 + cc * 8), LDSP((char*)W1s + p * 16), 16, 0, 0);
    __builtin_amdgcn_global_load_lds(GLB(W2T + row * 64 + cc * 8), LDSP((char*)W2s + p * 16), 16, 0, 0);
  }
  __syncthreads();

  const int tb = w * 32;
  bf16x8 af[2][2];
  #pragma unroll
  for (int mt = 0; mt < 2; ++mt) {
    const int row = tb + mt * 16 + l;
    #pragma unroll
    for (int kc = 0; kc < 2; ++kc)
      af[mt][kc] = *(const bf16x8*)(Vs + row * 64 + (((kc * 4 + quad) ^ (row & 7)) * 8));
  }
  bf16x8 w1f[4][2], w2f[4][2];
  #pragma unroll
  for (int nt = 0; nt < 4; ++nt) {
    const int row = nt * 16 + l;
    #pragma unroll
    for (int kc = 0; kc < 2; ++kc) {
      const int off = row * 64 + (((kc * 4 + quad) ^ (row & 7)) * 8);
      w1f[nt][kc] = *(const bf16x8*)(W1s + off);
      w2f[nt][kc] = *(const bf16x8*)(W2s + off);
    }
  }

  #pragma unroll
  for (int mt = 0; mt < 2; ++mt) {
    #pragma unroll
    for (int nt = 0; nt < 4; ++nt) {
      f32x4 a1 = __builtin_amdgcn_mfma_f32_16x16x32_bf16(af[mt][0], w1f[nt][0],
                                                         (f32x4){0.f,0.f,0.f,0.f}, 0, 0, 0);
      a1 = __builtin_amdgcn_mfma_f32_16x16x32_bf16(af[mt][1], w1f[nt][1], a1, 0, 0, 0);
      f32x4 a2 = __builtin_amdgcn_mfma_f32_16x16x32_bf16(af[mt][0], w2f[nt][0],
                                                         (f32x4){0.f,0.f,0.f,0.f}, 0, 0, 0);
      a2 = __builtin_amdgcn_mfma_f32_16x16x32_bf16(af[mt][1], w2f[nt][1], a2, 0, 0, 0);
      const int j = nt * 16 + l;
      const float bb1 = b1[j], bb2 = b2[j];
      bf16x4 g4;
      #pragma unroll
      for (int r = 0; r < 4; ++r) {
        const int t = tb + mt * 16 + quad * 4 + r;
        const float v = (float)Vs[t * 64 + (((j >> 3) ^ (t & 7)) * 8) + (j & 7)];
        const float g = (v + a1[r] + bb1) * (1.0f / (1.0f + __expf(-(a2[r] + bb2))));
        g4[r] = f2bf(g);
      }
      *(bf16x4*)(GVt + (size_t)(bh64 + j) * T_ + t0 + w * 32 + quad * 8 + mt * 4) = g4;
    }
  }
}

// ---------------- flash attention (causal), exp2-domain, static-shift softmax ----------------
// K-tile 32, SPLIT-2: block = (pair pr 0..7, split s 0..1, bh 0..31); each block = 34 k32-units.
// 8 waves x 16 q-rows (512 threads), LB(512,4). Raw v_exp_f32. Waves 0-3 stage K, 4-7 stage V.
// 4-slot LDS ring, prefetch distance 2, one barrier per 2 units. T5 setprio on MFMA.
__global__ __launch_bounds__(512, 4)
void flash_kernel(const bf16* __restrict__ Q, const bf16* __restrict__ Kb,
                  const bf16* __restrict__ GVt,
                  bf16* __restrict__ PartO, float* __restrict__ PartL) {
  __shared__ bf16 Kd[4][2048];   // [kt=32][d=64], 16B chunks XOR-swizzled by (row&7)
  __shared__ bf16 Vd[4][2048];   // [d=64][32 keys interleaved], chunks swizzled by (row>>1)&3
  const int tid = threadIdx.x, w = tid >> 6, lane = tid & 63;
  const int l = lane & 15, quad = lane >> 4;
  const int idx = blockIdx.x;
  const int bh = idx & 31;              // same bh -> same XCD: K/V L2 locality
  const int s = (idx >> 5) & 1;         // split-2
  const int pr = idx >> 6;              // 0..7
  const int qoA = pr, qoB = 15 - pr;
  const int nB = 4 * (qoB + 1);         // tile B's k32-unit count (36..64); always > 34
  const int u0 = 34 * s, u1 = u0 + 34;
  const int b = bh >> 4, h = bh & 15;
  const int bT = b * T_, hc = h * 64, bh64 = bh * 64;
  const int swz = l & 7;
  const int swv = (l >> 1) & 3;
  const size_t srowbase = (size_t)(s * 32 + bh) * 2048;   // s in {0,1}: rows [2][65536]

  f32x4 o[4];             // O^T accumulator: [db], lane: q=l, d=db*16+quad*4+r
  float lsum;
  bf16x8 qa[2];
  int q0cur;

  auto resetacc = [&]() {
    #pragma unroll
    for (int db = 0; db < 4; ++db) o[db] = (f32x4){0.f, 0.f, 0.f, 0.f};
    lsum = 0.f;
  };
  auto loadqa = [&](int q0) {
    const int rb0 = q0 + w * 16;        // wave covers 16 q-rows
    #pragma unroll
    for (int kc = 0; kc < 2; ++kc)
      qa[kc] = *(const bf16x8*)(Q + (size_t)(bT + rb0 + l) * C_ + hc + kc * 32 + quad * 8);
  };
  auto u2kt = [&](int u, int& q0, int& kt) {
    if (u < nB) { q0 = qoB * 128; kt = u * 32; }
    else        { q0 = qoA * 128; kt = (u - nB) * 32; }
  };
  auto stage_u = [&](int u) {           // stage unit u's K/V tiles into ring slot u&3
    int q0n, ktn;
    u2kt(u, q0n, ktn);
    const int bufn = u & 3;
    if (tid < 256) {                    // waves 0-3: K tile (4KB = 256 x 16B)
      const int rowk = tid >> 3, ck = (tid & 7) ^ (rowk & 7);
      __builtin_amdgcn_global_load_lds(GLB(Kb + (size_t)(bT + ktn + rowk) * C_ + hc + ck * 8),
                                       LDSP((char*)&Kd[bufn][0] + tid * 16), 16, 0, 0);
    } else {                            // waves 4-7: V tile (4KB)
      const int t2 = tid - 256;
      const int rowv = t2 >> 2, cv = (t2 & 3) ^ ((rowv >> 1) & 3);
      __builtin_amdgcn_global_load_lds(GLB(GVt + (size_t)(bh64 + rowv) * T_ + ktn + cv * 8),
                                       LDSP((char*)&Vd[bufn][0] + t2 * 16), 16, 0, 0);
    }
  };
  auto flush = [&](int q0) {           // write partials (bf16 O, fp32 lsum) for 16 rows/wave
    const int rb0f = q0 + w * 16;
    float ls = lsum;
    ls += __shfl_xor(ls, 16, 64);
    ls += __shfl_xor(ls, 32, 64);
    const int t = rb0f + l;
    const size_t ro = (srowbase + t) * 64;
    #pragma unroll
    for (int db = 0; db < 4; ++db) {
      bf16x4 ov;
      #pragma unroll
      for (int r = 0; r < 4; ++r) ov[r] = f2bf(o[db][r]);
      *(bf16x4*)(PartO + ro + db * 16 + quad * 4) = ov;
    }
    if (quad == 0) PartL[srowbase + t] = ls;
  };
  auto compute_u = [&](int u) {        // softmax-attend one 32-key unit from slot u&3
    int q0u, ktu;
    u2kt(u, q0u, ktu);
    if (q0u != q0cur) {                 // pair boundary: flush tile B, switch to tile A
      flush(q0cur);
      resetacc();
      q0cur = q0u;
      loadqa(q0cur);
    }
    const int rb0 = q0cur + w * 16;

    if (ktu <= rb0 + 15) {  // wave-uniform: skip fully-masked units
      const bf16* Kc = &Kd[u & 3][0];
      const bf16* Vc = &Vd[u & 3][0];

      bf16x8 kf[2][2];      // K A-frags, 2 x 16-key tiles
      #pragma unroll
      for (int c = 0; c < 2; ++c)
        #pragma unroll
        for (int kc = 0; kc < 2; ++kc)
          kf[c][kc] = *(const bf16x8*)(Kc + (c * 16 + l) * 64 + (((4 * kc + quad) ^ swz) * 8));

      bf16x8 vfr[4];        // V^T A-frags: ONE b128 each (interleaved chunk)
      #pragma unroll
      for (int db = 0; db < 4; ++db)
        vfr[db] = *(const bf16x8*)(Vc + (db * 16 + l) * 32 + ((quad ^ swv) * 8));

      const int qrow = rb0 + l;
      f32x4 sv[2];
      __builtin_amdgcn_s_setprio(1);
      #pragma unroll
      for (int c = 0; c < 2; ++c) {
        sv[c] = __builtin_amdgcn_mfma_f32_16x16x32_bf16(kf[c][0], qa[0],
                                                        (f32x4){0.f,0.f,0.f,0.f}, 0, 0, 0);
        sv[c] = __builtin_amdgcn_mfma_f32_16x16x32_bf16(kf[c][1], qa[1], sv[c], 0, 0, 0);
      }
      __builtin_amdgcn_s_setprio(0);
      #pragma unroll
      for (int c = 0; c < 2; ++c)
        if (ktu + c * 16 + 15 > rb0) {  // diagonal: mask key > q
          const int kb = ktu + c * 16 + quad * 4;
          #pragma unroll
          for (int r = 0; r < 4; ++r)
            if (kb + r > qrow) sv[c][r] = -1e30f;
        }
      float p[2][4];
      float ps = 0.f;
      #pragma unroll
      for (int c = 0; c < 2; ++c)
        #pragma unroll
        for (int r = 0; r < 4; ++r) {
          p[c][r] = __builtin_amdgcn_exp2f(sv[c][r]);   // raw v_exp_f32
          ps += p[c][r];
        }
      lsum += ps;

      union { unsigned u[4]; bf16x8 v8; } pf;   // slot j: key (j>=4?16:0)+quad*4+(j&3)
      pf.u[0] = pk2bf(p[0][0], p[0][1]);
      pf.u[1] = pk2bf(p[0][2], p[0][3]);
      pf.u[2] = pk2bf(p[1][0], p[1][1]);
      pf.u[3] = pk2bf(p[1][2], p[1][3]);
      __builtin_amdgcn_s_setprio(1);
      #pragma unroll
      for (int db = 0; db < 4; ++db)
        o[db] = __builtin_amdgcn_mfma_f32_16x16x32_bf16(vfr[db], pf.v8, o[db], 0, 0, 0);
      __builtin_amdgcn_s_setprio(0);
    }
  };

  int kt0;
  u2kt(u0, q0cur, kt0);
  resetacc();
  loadqa(q0cur);
  stage_u(u0);
  stage_u(u0 + 1);
  __syncthreads();   // own-wave vmcnt(0) drain + barrier: slots u0, u0+1 ready for ALL waves

  for (int u = u0; u < u1; u += 2) {
    if (u + 2 < u1) stage_u(u + 2);     // async prefetch into slots (u+2)&3, (u+3)&3
    if (u + 3 < u1) stage_u(u + 3);
    compute_u(u);
    compute_u(u + 1);
    __syncthreads();   // drains this wave's prefetch; all waves past reads of slots u,u+1
  }

  flush(q0cur);
  resetacc();
  if (q0cur == qoB * 128)      flush(qoA * 128);  // s=0: never reached tile A -> zero partials
  else if (u0 >= nB)           flush(qoB * 128);  // (unreachable for split-2; kept for safety)
}

// ---------------- combine partials: Y = sum(O_s)/sum(l_s), cast bf16 (split-2) ----------------
__global__ __launch_bounds__(256)
void combine_kernel(const bf16* __restrict__ PartO, const float* __restrict__ PartL,
                    bf16* __restrict__ Y) {
  const int e = blockIdx.x * 256 + threadIdx.x;   // 32*2048*16 threads (4 d each)
  const int dg = e & 15, row = e >> 4;            // row = bh*2048 + t
  const int bh = row >> 11, t = row & 2047;
  float ls = 0.f;
  float acc[4] = {0.f, 0.f, 0.f, 0.f};
  #pragma unroll
  for (int s = 0; s < 2; ++s) {
    ls += PartL[s * 65536 + row];
    const bf16x4 ov = *(const bf16x4*)(PartO + ((size_t)(s * 65536 + row)) * 64 + dg * 4);
    #pragma unroll
    for (int r = 0; r < 4; ++r) acc[r] += (float)ov[r];
  }
  const float inv = 1.0f / ls;
  const int b = bh >> 4, h = bh & 15;
  bf16x4 y;
  #pragma unroll
  for (int r = 0; r < 4; ++r) y[r] = f2bf(acc[r] * inv);
  *(bf16x4*)(Y + (size_t)(b * T_ + t) * C_ + h * 64 + dg * 4) = y;
}

// ---------------- launch ----------------
extern "C" void kernel_launch(void* const* d_in, const int* in_sizes, int n_in,
                              void* d_out, int out_size, void* d_ws, size_t ws_size,
                              hipStream_t stream) {
  const float* x      = (const float*)d_in[0];
  const float* W_attn = (const float*)d_in[1];
  const float* b_attn = (const float*)d_in[2];
  const float* W_l1   = (const float*)d_in[3];
  const float* b_l1   = (const float*)d_in[4];
  const float* W_l2   = (const float*)d_in[5];
  const float* b_l2   = (const float*)d_in[6];
  const float* W_proj = (const float*)d_in[7];
  const float* b_proj = (const float*)d_in[8];
  float* out = (float*)d_out;

  char* ws = (char*)d_ws;
  bf16* Xbf = (bf16*)(ws);                          //  8 MB  [M][C]
  bf16* WaT = (bf16*)(ws + ((size_t)8  << 20));     //  6 MB  [3C][C]
  bf16* WpT = (bf16*)(ws + ((size_t)14 << 20));     //  2 MB  [C][C]
  bf16* Qbf = (bf16*)(ws + ((size_t)16 << 20));     //  8 MB
  bf16* Kbf = (bf16*)(ws + ((size_t)24 << 20));     //  8 MB
  bf16* Vbf = (bf16*)(ws + ((size_t)32 << 20));     //  8 MB
  bf16* GVt = (bf16*)(ws + ((size_t)40 << 20));     //  8 MB  [b][h][j][t interleaved]
  bf16* Ybf = (bf16*)(ws + ((size_t)48 << 20));     //  8 MB
  bf16* PartO = (bf16*)(ws + ((size_t)56 << 20));   // 16 MB  [2][32*2048][64] bf16
  float* PartL = (float*)(ws + ((size_t)88 << 20)); // 0.5 MB [2][32*2048] fp32
  bf16* W1T = (bf16*)(ws + ((size_t)89 << 20));     //  8 KB  [j][d]
  bf16* W2T = (bf16*)(ws + ((size_t)89 << 20) + 8192);

  prep_kernel<<<4096 + 3072 + 1024 + 32, 256, 0, stream>>>(
      x, Xbf, W_attn, WaT, W_proj, WpT, W_l1, W_l2, W1T, W2T);

  gemm128_qkv<<<768, 256, 0, stream>>>(Xbf, WaT, b_attn, Qbf, Kbf, Vbf);

  gate_kernel<<<dim3(T_ / 128, B_ * H_), 256, 0, stream>>>(Vbf, W1T, b_l1, W2T, b_l2, GVt);

  flash_kernel<<<512, 512, 0, stream>>>(Qbf, Kbf, GVt, PartO, PartL);

  combine_kernel<<<32 * 2048 * 16 / 256, 256, 0, stream>>>(PartO, PartL, Ybf);

  gemm128_proj<<<256, 256, 0, stream>>>(Ybf, WpT, b_proj, out);

  (void)in_sizes; (void)n_in; (void)out_size; (void)ws_size;
}

// Round 13
// 186.466 us; speedup vs baseline: 1.0230x; 1.0230x over previous
//
#include <hip/hip_runtime.h>

#define B_  2
#define T_  2048
#define C_  1024
#define H_  16
#define HS_ 64
#define M_  4096   // B_*T_
#define N3_ 3072

typedef __bf16 bf16;
typedef bf16  bf16x4 __attribute__((ext_vector_type(4)));
typedef bf16  bf16x8 __attribute__((ext_vector_type(8)));
typedef float f32x4  __attribute__((ext_vector_type(4)));

__device__ __forceinline__ bf16 f2bf(float x) {
  union { float f; unsigned u; } v; v.f = x;
  unsigned r = (v.u + 0x7FFFu + ((v.u >> 16) & 1u)) >> 16;
  union { unsigned short s; bf16 b; } o; o.s = (unsigned short)r;
  return o.b;
}

// pack two fp32 -> two bf16 (round via +0x8000), lane-local, ~3 VALU ops
__device__ __forceinline__ unsigned pk2bf(float lo, float hi) {
  union { float f; unsigned u; } a, b;
  a.f = lo; b.f = hi;
  return ((a.u + 0x8000u) >> 16) | ((b.u + 0x8000u) & 0xFFFF0000u);
}

#define GLB(p) ((const __attribute__((address_space(1))) void*)(p))
#define LDSP(p) ((__attribute__((address_space(3))) void*)(p))
#define VMCNT(n) asm volatile("s_waitcnt vmcnt(" #n ")" ::: "memory")
#define BAR() asm volatile("s_barrier" ::: "memory")

// ---------------- fused prep: cast x, transpose W_attn/W_proj, transpose W_l1/l2 ----------------
//   [0,4096)            cast_x  (f32x4 -> bf16x4)
//   [4096, 4096+3072)   transpose_cast W_attn [1024][3072] -> WaT [3072][1024]
//   [7168, 7168+1024)   transpose_cast W_proj [1024][1024] -> WpT
//   [8192, 8192+32)     cast_wl (W_l1/W_l2 64x64 transpose)
__global__ __launch_bounds__(256)
void prep_kernel(const float* __restrict__ x, bf16* __restrict__ Xbf,
                 const float* __restrict__ W_attn, bf16* __restrict__ WaT,
                 const float* __restrict__ W_proj, bf16* __restrict__ WpT,
                 const float* __restrict__ W1, const float* __restrict__ W2,
                 bf16* __restrict__ W1T, bf16* __restrict__ W2T) {
  __shared__ float tile[32][33];
  int bid = blockIdx.x;
  const int tid = threadIdx.x;
  if (bid < 4096) {                       // ---- cast_x
    const int i = bid * 256 + tid;        // n4 = 4096*256 exactly
    float4 v = ((const float4*)x)[i];
    bf16 o[4] = {f2bf(v.x), f2bf(v.y), f2bf(v.z), f2bf(v.w)};
    *(uint2*)(Xbf + (size_t)i * 4) = *(uint2*)o;
    return;
  }
  bid -= 4096;
  if (bid < 3072 + 1024) {                // ---- transposes (32x32 tile, 256 thr as 32x8)
    const float* in; bf16* out; int R, Cc, bx, by;
    if (bid < 3072) { in = W_attn; out = WaT; R = C_; Cc = N3_; bx = bid % 96; by = bid / 96; }
    else { const int b2 = bid - 3072; in = W_proj; out = WpT; R = C_; Cc = C_; bx = b2 & 31; by = b2 >> 5; }
    const int c0 = bx * 32, r0 = by * 32;
    const int tx = tid & 31, ty = tid >> 5;
    #pragma unroll
    for (int i = ty; i < 32; i += 8)
      tile[i][tx] = in[(size_t)(r0 + i) * Cc + c0 + tx];
    __syncthreads();
    #pragma unroll
    for (int i = ty; i < 32; i += 8)
      out[(size_t)(c0 + i) * R + r0 + tx] = f2bf(tile[tx][i]);
    return;
  }
  bid -= 4096;                            // ---- cast_wl: 32 blocks
  const int t2 = bid * 256 + tid;         // 8192 total
  const int m = t2 >> 12, e = t2 & 4095;
  const int j = e >> 6, d = e & 63;
  const float* src = m ? W2 : W1;
  bf16* dst = m ? W2T : W1T;
  dst[e] = f2bf(src[d * 64 + j]);
}

// ------------- 256x256 8-wave pipelined QKV GEMM — 1 barrier + 1 vmcnt per K-tile -------------
// C = A[M,1024] * Bt[N,1024]^T + bias, split epilogue Q/K/V (block-uniform segment).
// Ledger per tile t: VMCNT(0) [t's loads had a full tile to land] -> BAR [slot visible;
// all waves done reading slot ns] -> issue ALL t+1 staging (8 gload_lds) -> 64 MFMA.
// 17 barriers total. R12 lesson: 128² tiles (768 blocks, full CU coverage) REGRESSED +4.3us
// — 2x staged bytes + half the MFMA per barrier outweigh the 64 idle CUs. 256² stays.
__global__ __launch_bounds__(512, 2)
void gemm256_qkv(const bf16* __restrict__ A, const bf16* __restrict__ Bt,
                 const float* __restrict__ bias,
                 bf16* __restrict__ Qo, bf16* __restrict__ Ko, bf16* __restrict__ Vo) {
  constexpr int K = C_;          // 1024
  constexpr int NT = K / 64;     // 16 K-tiles
  __shared__ __attribute__((aligned(16))) char SM[131072];  // [slot][A 32KB | B 32KB]
  const int tid = threadIdx.x;
  const int lane = tid & 63, w = tid >> 6;
  const int l = lane & 15, quad = lane >> 4;
  const int lsw = l & 7;
  const int wm = (w >> 1) * 64;    // wave tile 64 rows x 128 cols (4M x 2N wave grid)
  const int wn = (w & 1) * 128;

  // XCD-chunked block swizzle: 192 blocks, 24 per XCD (2 consecutive by-rows)
  const int bid = blockIdx.x;
  const int xcd = bid & 7, q = bid >> 3;
  const int by = xcd * 2 + q / 12, bx = q - (q / 12) * 12;
  const int m0 = by * 256, n0 = bx * 256;

  // staging coords: source col pre-swizzled so linear LDS dest + swizzled read match (rule 21)
  const int srow = tid >> 3;                              // 0..63
  const int scol = ((tid & 7) ^ ((tid >> 3) & 7)) * 8;    // bf16 elements
  const bf16* Asrc = A + (size_t)(m0 + srow) * K + scol;
  const bf16* Bsrc = Bt + (size_t)(n0 + srow) * K + scol;
  char* dstb = SM + tid * 16;

  auto stg_tile = [&](int slot, int t) {    // all 8 loads for one K-tile (A 32KB + B 32KB)
    #pragma unroll
    for (int h = 0; h < 2; ++h)
      #pragma unroll
      for (int i = 0; i < 2; ++i)
        __builtin_amdgcn_global_load_lds(
            GLB(Asrc + (size_t)(h * 128 + i * 64) * K + t * 64),
            LDSP(dstb + slot * 65536 + h * 16384 + i * 8192), 16, 0, 0);
    #pragma unroll
    for (int h = 0; h < 2; ++h)
      #pragma unroll
      for (int i = 0; i < 2; ++i)
        __builtin_amdgcn_global_load_lds(
            GLB(Bsrc + (size_t)(h * 128 + i * 64) * K + t * 64),
            LDSP(dstb + slot * 65536 + 32768 + h * 16384 + i * 8192), 16, 0, 0);
  };
  auto ldsA = [&](int slot, int mi, int kk) {
    return *(const bf16x8*)(SM + slot * 65536 + (wm + mi * 16 + l) * 128 +
                            (((kk * 4 + quad) ^ lsw) * 16));
  };
  auto ldsB = [&](int slot, int ni, int kk) {
    return *(const bf16x8*)(SM + slot * 65536 + 32768 + (wn + ni * 16 + l) * 128 +
                            (((kk * 4 + quad) ^ lsw) * 16));
  };

  f32x4 acc[4][8];
  #pragma unroll
  for (int mi = 0; mi < 4; ++mi)
    #pragma unroll
    for (int ni = 0; ni < 8; ++ni)
      acc[mi][ni] = (f32x4){0.f, 0.f, 0.f, 0.f};

  bf16x8 af[4][2];
  auto phase_mfma = [&](bf16x8 (&bp)[2][2], int nbase) {
    __builtin_amdgcn_s_setprio(1);
    #pragma unroll
    for (int mi = 0; mi < 4; ++mi)
      #pragma unroll
      for (int nj = 0; nj < 2; ++nj) {
        acc[mi][nbase + nj] = __builtin_amdgcn_mfma_f32_16x16x32_bf16(
            af[mi][0], bp[nj][0], acc[mi][nbase + nj], 0, 0, 0);
        acc[mi][nbase + nj] = __builtin_amdgcn_mfma_f32_16x16x32_bf16(
            af[mi][1], bp[nj][1], acc[mi][nbase + nj], 0, 0, 0);
      }
    __builtin_amdgcn_s_setprio(0);
  };

  // prologue: tile 0 -> slot 0
  stg_tile(0, 0);

  for (int t = 0; t < NT; ++t) {
    const int st = t & 1, ns = st ^ 1;
    VMCNT(0);   // t's loads done (issued a full tile ago; boundary wait ~free)
    BAR();      // slot st visible to all waves; all waves done reading slot ns (tile t-1)
    if (t + 1 < NT) stg_tile(ns, t + 1);   // overwrites t-1's slot: safe post-barrier

    #pragma unroll
    for (int mi = 0; mi < 4; ++mi) {
      af[mi][0] = ldsA(st, mi, 0);
      af[mi][1] = ldsA(st, mi, 1);
    }
    #pragma unroll
    for (int g = 0; g < 4; ++g) {
      bf16x8 bp[2][2];
      #pragma unroll
      for (int nj = 0; nj < 2; ++nj) {
        bp[nj][0] = ldsB(st, g * 2 + nj, 0);
        bp[nj][1] = ldsB(st, g * 2 + nj, 1);
      }
      phase_mfma(bp, g * 2);
    }
  }

  // epilogue: segment (Q/K/V) is block-uniform since 256 | 1024
  const int seg = n0 >> 10;
  const int ncol0 = (n0 & 1023) + wn;
  #pragma unroll
  for (int mi = 0; mi < 4; ++mi) {
    #pragma unroll
    for (int ni = 0; ni < 8; ++ni) {
      const float bb = bias[n0 + wn + ni * 16 + l];
      #pragma unroll
      for (int r = 0; r < 4; ++r) {
        const int row = m0 + wm + mi * 16 + quad * 4 + r;
        const float v = acc[mi][ni][r] + bb;
        const size_t idx = (size_t)row * C_ + ncol0 + ni * 16 + l;
        if (seg == 0)      Qo[idx] = f2bf(v * 0.1803368801f);
        else if (seg == 1) Ko[idx] = f2bf(v);
        else               Vo[idx] = f2bf(v);
      }
    }
  }
}

// ------------- 128x128 4-wave pipelined proj GEMM — same 1-barrier/tile ledger -------------
// Fo[4096][1024] = A[4096,1024] @ Bt[1024,1024]^T + bias (fp32 out).
// Grid 256 blocks. 2 LDS slots x (A 16KB + B 16KB) = 64KB -> 2 blocks/CU possible.
__global__ __launch_bounds__(256, 2)
void gemm128_proj(const bf16* __restrict__ A, const bf16* __restrict__ Bt,
                  const float* __restrict__ bias, float* __restrict__ Fo) {
  constexpr int K = C_;          // 1024
  constexpr int NT = K / 64;     // 16 K-tiles
  __shared__ __attribute__((aligned(16))) char SM[65536];  // [slot][A 16KB | B 16KB]
  const int tid = threadIdx.x;
  const int lane = tid & 63, w = tid >> 6;
  const int l = lane & 15, quad = lane >> 4;
  const int lsw = l & 7;
  const int wm = (w >> 1) * 64, wn = (w & 1) * 64;   // 2x2 wave grid, wave tile 64x64

  // XCD-chunked swizzle: 256 blocks, 32/XCD
  const int bid = blockIdx.x;
  const int lin = (bid & 7) * 32 + (bid >> 3);
  const int by = lin >> 3, bx = lin & 7;             // 32 x 8
  const int m0 = by * 128, n0 = bx * 128;

  const int srow = tid >> 3;                              // 0..31
  const int scol = ((tid & 7) ^ ((tid >> 3) & 7)) * 8;    // pre-swizzled source col
  const bf16* Asrc = A + (size_t)(m0 + srow) * K + scol;
  const bf16* Bsrc = Bt + (size_t)(n0 + srow) * K + scol;
  char* dstb = SM + tid * 16;

  auto stg_tile = [&](int slot, int t) {    // all 8 loads for one K-tile (A 16KB + B 16KB)
    #pragma unroll
    for (int h = 0; h < 2; ++h)
      #pragma unroll
      for (int i = 0; i < 2; ++i)
        __builtin_amdgcn_global_load_lds(
            GLB(Asrc + (size_t)(h * 64 + i * 32) * K + t * 64),
            LDSP(dstb + slot * 32768 + h * 8192 + i * 4096), 16, 0, 0);
    #pragma unroll
    for (int h = 0; h < 2; ++h)
      #pragma unroll
      for (int i = 0; i < 2; ++i)
        __builtin_amdgcn_global_load_lds(
            GLB(Bsrc + (size_t)(h * 64 + i * 32) * K + t * 64),
            LDSP(dstb + slot * 32768 + 16384 + h * 8192 + i * 4096), 16, 0, 0);
  };
  auto ldsA = [&](int slot, int mi, int kk) {
    return *(const bf16x8*)(SM + slot * 32768 + (wm + mi * 16 + l) * 128 +
                            (((kk * 4 + quad) ^ lsw) * 16));
  };
  auto ldsB = [&](int slot, int ni, int kk) {
    return *(const bf16x8*)(SM + slot * 32768 + 16384 + (wn + ni * 16 + l) * 128 +
                            (((kk * 4 + quad) ^ lsw) * 16));
  };

  f32x4 acc[4][4];
  #pragma unroll
  for (int mi = 0; mi < 4; ++mi)
    #pragma unroll
    for (int ni = 0; ni < 4; ++ni)
      acc[mi][ni] = (f32x4){0.f, 0.f, 0.f, 0.f};

  bf16x8 af[4][2];
  auto phase_mfma = [&](bf16x8 (&bp)[2][2], int nbase) {
    __builtin_amdgcn_s_setprio(1);
    #pragma unroll
    for (int mi = 0; mi < 4; ++mi)
      #pragma unroll
      for (int nj = 0; nj < 2; ++nj) {
        acc[mi][nbase + nj] = __builtin_amdgcn_mfma_f32_16x16x32_bf16(
            af[mi][0], bp[nj][0], acc[mi][nbase + nj], 0, 0, 0);
        acc[mi][nbase + nj] = __builtin_amdgcn_mfma_f32_16x16x32_bf16(
            af[mi][1], bp[nj][1], acc[mi][nbase + nj], 0, 0, 0);
      }
    __builtin_amdgcn_s_setprio(0);
  };

  stg_tile(0, 0);

  for (int t = 0; t < NT; ++t) {
    const int st = t & 1, ns = st ^ 1;
    VMCNT(0);
    BAR();
    if (t + 1 < NT) stg_tile(ns, t + 1);

    #pragma unroll
    for (int mi = 0; mi < 4; ++mi) {
      af[mi][0] = ldsA(st, mi, 0);
      af[mi][1] = ldsA(st, mi, 1);
    }
    #pragma unroll
    for (int g = 0; g < 2; ++g) {
      bf16x8 bp[2][2];
      #pragma unroll
      for (int nj = 0; nj < 2; ++nj) {
        bp[nj][0] = ldsB(st, g * 2 + nj, 0);
        bp[nj][1] = ldsB(st, g * 2 + nj, 1);
      }
      phase_mfma(bp, g * 2);
    }
  }

  #pragma unroll
  for (int mi = 0; mi < 4; ++mi) {
    #pragma unroll
    for (int ni = 0; ni < 4; ++ni) {
      const float bb = bias[n0 + wn + ni * 16 + l];
      #pragma unroll
      for (int r = 0; r < 4; ++r) {
        const int row = m0 + wm + mi * 16 + quad * 4 + r;
        Fo[(size_t)row * C_ + n0 + wn + ni * 16 + l] = acc[mi][ni][r] + bb;
      }
    }
  }
}

// ---------------- v-gating via MFMA: gv = (v + v@W1 + b1) * sigmoid(v@W2 + b2) ----------------
// Writes GVt [b][h][j][t'] with INTERLEAVED key order within each 32-t block.
__global__ __launch_bounds__(256)
void gate_kernel(const bf16* __restrict__ V, const bf16* __restrict__ W1T,
                 const float* __restrict__ b1, const bf16* __restrict__ W2T,
                 const float* __restrict__ b2, bf16* __restrict__ GVt) {
  __shared__ bf16 Vs[128 * 64];
  __shared__ bf16 W1s[64 * 64];
  __shared__ bf16 W2s[64 * 64];
  const int tid = threadIdx.x, w = tid >> 6, lane = tid & 63;
  const int l = lane & 15, quad = lane >> 4;
  const int bh = blockIdx.y;
  const int t0 = blockIdx.x * 128;
  const int b = bh >> 4, h = bh & 15;
  const int bT = b * T_, hc = h * 64, bh64 = bh * 64;

  #pragma unroll
  for (int i = 0; i < 4; ++i) {
    const int p = tid + i * 256;
    const int row = p >> 3, cc = (p & 7) ^ (row & 7);
    const bf16* gv = V + (size_t)(bT + t0 + row) * C_ + hc + cc * 8;
    __builtin_amdgcn_global_load_lds(GLB(gv), LDSP((char*)Vs + p * 16), 16, 0, 0);
  }
  #pragma unroll
  for (int i = 0; i < 2; ++i) {
    const int p = tid + i * 256;
    const int row = p >> 3, cc = (p & 7) ^ (row & 7);
    __builtin_amdgcn_global_load_lds(GLB(W1T + row * 64 + cc * 8), LDSP((char*)W1s + p * 16), 16, 0, 0);
    __builtin_amdgcn_global_load_lds(GLB(W2T + row * 64 + cc * 8), LDSP((char*)W2s + p * 16), 16, 0, 0);
  }
  __syncthreads();

  const int tb = w * 32;
  bf16x8 af[2][2];
  #pragma unroll
  for (int mt = 0; mt < 2; ++mt) {
    const int row = tb + mt * 16 + l;
    #pragma unroll
    for (int kc = 0; kc < 2; ++kc)
      af[mt][kc] = *(const bf16x8*)(Vs + row * 64 + (((kc * 4 + quad) ^ (row & 7)) * 8));
  }
  bf16x8 w1f[4][2], w2f[4][2];
  #pragma unroll
  for (int nt = 0; nt < 4; ++nt) {
    const int row = nt * 16 + l;
    #pragma unroll
    for (int kc = 0; kc < 2; ++kc) {
      const int off = row * 64 + (((kc * 4 + quad) ^ (row & 7)) * 8);
      w1f[nt][kc] = *(const bf16x8*)(W1s + off);
      w2f[nt][kc] = *(const bf16x8*)(W2s + off);
    }
  }

  #pragma unroll
  for (int mt = 0; mt < 2; ++mt) {
    #pragma unroll
    for (int nt = 0; nt < 4; ++nt) {
      f32x4 a1 = __builtin_amdgcn_mfma_f32_16x16x32_bf16(af[mt][0], w1f[nt][0],
                                                         (f32x4){0.f,0.f,0.f,0.f}, 0, 0, 0);
      a1 = __builtin_amdgcn_mfma_f32_16x16x32_bf16(af[mt][1], w1f[nt][1], a1, 0, 0, 0);
      f32x4 a2 = __builtin_amdgcn_mfma_f32_16x16x32_bf16(af[mt][0], w2f[nt][0],
                                                         (f32x4){0.f,0.f,0.f,0.f}, 0, 0, 0);
      a2 = __builtin_amdgcn_mfma_f32_16x16x32_bf16(af[mt][1], w2f[nt][1], a2, 0, 0, 0);
      const int j = nt * 16 + l;
      const float bb1 = b1[j], bb2 = b2[j];
      bf16x4 g4;
      #pragma unroll
      for (int r = 0; r < 4; ++r) {
        const int t = tb + mt * 16 + quad * 4 + r;
        const float v = (float)Vs[t * 64 + (((j >> 3) ^ (t & 7)) * 8) + (j & 7)];
        const float g = (v + a1[r] + bb1) * (1.0f / (1.0f + __expf(-(a2[r] + bb2))));
        g4[r] = f2bf(g);
      }
      *(bf16x4*)(GVt + (size_t)(bh64 + j) * T_ + t0 + w * 32 + quad * 8 + mt * 4) = g4;
    }
  }
}

// ---------------- flash attention (causal), exp2-domain, static-shift softmax ----------------
// K-tile 32, SPLIT-2: block = (pair pr 0..7, split s 0..1, bh 0..31); each block = 34 k32-units.
// 8 waves x 16 q-rows (512 threads), LB(512,4). Raw v_exp_f32. Waves 0-3 stage K, 4-7 stage V.
// 4-slot LDS ring, prefetch distance 2, one barrier per 2 units. T5 setprio on MFMA.
__global__ __launch_bounds__(512, 4)
void flash_kernel(const bf16* __restrict__ Q, const bf16* __restrict__ Kb,
                  const bf16* __restrict__ GVt,
                  bf16* __restrict__ PartO, float* __restrict__ PartL) {
  __shared__ bf16 Kd[4][2048];   // [kt=32][d=64], 16B chunks XOR-swizzled by (row&7)
  __shared__ bf16 Vd[4][2048];   // [d=64][32 keys interleaved], chunks swizzled by (row>>1)&3
  const int tid = threadIdx.x, w = tid >> 6, lane = tid & 63;
  const int l = lane & 15, quad = lane >> 4;
  const int idx = blockIdx.x;
  const int bh = idx & 31;              // same bh -> same XCD: K/V L2 locality
  const int s = (idx >> 5) & 1;         // split-2
  const int pr = idx >> 6;              // 0..7
  const int qoA = pr, qoB = 15 - pr;
  const int nB = 4 * (qoB + 1);         // tile B's k32-unit count (36..64); always > 34
  const int u0 = 34 * s, u1 = u0 + 34;
  const int b = bh >> 4, h = bh & 15;
  const int bT = b * T_, hc = h * 64, bh64 = bh * 64;
  const int swz = l & 7;
  const int swv = (l >> 1) & 3;
  const size_t srowbase = (size_t)(s * 32 + bh) * 2048;   // s in {0,1}: rows [2][65536]

  f32x4 o[4];             // O^T accumulator: [db], lane: q=l, d=db*16+quad*4+r
  float lsum;
  bf16x8 qa[2];
  int q0cur;

  auto resetacc = [&]() {
    #pragma unroll
    for (int db = 0; db < 4; ++db) o[db] = (f32x4){0.f, 0.f, 0.f, 0.f};
    lsum = 0.f;
  };
  auto loadqa = [&](int q0) {
    const int rb0 = q0 + w * 16;        // wave covers 16 q-rows
    #pragma unroll
    for (int kc = 0; kc < 2; ++kc)
      qa[kc] = *(const bf16x8*)(Q + (size_t)(bT + rb0 + l) * C_ + hc + kc * 32 + quad * 8);
  };
  auto u2kt = [&](int u, int& q0, int& kt) {
    if (u < nB) { q0 = qoB * 128; kt = u * 32; }
    else        { q0 = qoA * 128; kt = (u - nB) * 32; }
  };
  auto stage_u = [&](int u) {           // stage unit u's K/V tiles into ring slot u&3
    int q0n, ktn;
    u2kt(u, q0n, ktn);
    const int bufn = u & 3;
    if (tid < 256) {                    // waves 0-3: K tile (4KB = 256 x 16B)
      const int rowk = tid >> 3, ck = (tid & 7) ^ (rowk & 7);
      __builtin_amdgcn_global_load_lds(GLB(Kb + (size_t)(bT + ktn + rowk) * C_ + hc + ck * 8),
                                       LDSP((char*)&Kd[bufn][0] + tid * 16), 16, 0, 0);
    } else {                            // waves 4-7: V tile (4KB)
      const int t2 = tid - 256;
      const int rowv = t2 >> 2, cv = (t2 & 3) ^ ((rowv >> 1) & 3);
      __builtin_amdgcn_global_load_lds(GLB(GVt + (size_t)(bh64 + rowv) * T_ + ktn + cv * 8),
                                       LDSP((char*)&Vd[bufn][0] + t2 * 16), 16, 0, 0);
    }
  };
  auto flush = [&](int q0) {           // write partials (bf16 O, fp32 lsum) for 16 rows/wave
    const int rb0f = q0 + w * 16;
    float ls = lsum;
    ls += __shfl_xor(ls, 16, 64);
    ls += __shfl_xor(ls, 32, 64);
    const int t = rb0f + l;
    const size_t ro = (srowbase + t) * 64;
    #pragma unroll
    for (int db = 0; db < 4; ++db) {
      bf16x4 ov;
      #pragma unroll
      for (int r = 0; r < 4; ++r) ov[r] = f2bf(o[db][r]);
      *(bf16x4*)(PartO + ro + db * 16 + quad * 4) = ov;
    }
    if (quad == 0) PartL[srowbase + t] = ls;
  };
  auto compute_u = [&](int u) {        // softmax-attend one 32-key unit from slot u&3
    int q0u, ktu;
    u2kt(u, q0u, ktu);
    if (q0u != q0cur) {                 // pair boundary: flush tile B, switch to tile A
      flush(q0cur);
      resetacc();
      q0cur = q0u;
      loadqa(q0cur);
    }
    const int rb0 = q0cur + w * 16;

    if (ktu <= rb0 + 15) {  // wave-uniform: skip fully-masked units
      const bf16* Kc = &Kd[u & 3][0];
      const bf16* Vc = &Vd[u & 3][0];

      bf16x8 kf[2][2];      // K A-frags, 2 x 16-key tiles
      #pragma unroll
      for (int c = 0; c < 2; ++c)
        #pragma unroll
        for (int kc = 0; kc < 2; ++kc)
          kf[c][kc] = *(const bf16x8*)(Kc + (c * 16 + l) * 64 + (((4 * kc + quad) ^ swz) * 8));

      bf16x8 vfr[4];        // V^T A-frags: ONE b128 each (interleaved chunk)
      #pragma unroll
      for (int db = 0; db < 4; ++db)
        vfr[db] = *(const bf16x8*)(Vc + (db * 16 + l) * 32 + ((quad ^ swv) * 8));

      const int qrow = rb0 + l;
      f32x4 sv[2];
      __builtin_amdgcn_s_setprio(1);
      #pragma unroll
      for (int c = 0; c < 2; ++c) {
        sv[c] = __builtin_amdgcn_mfma_f32_16x16x32_bf16(kf[c][0], qa[0],
                                                        (f32x4){0.f,0.f,0.f,0.f}, 0, 0, 0);
        sv[c] = __builtin_amdgcn_mfma_f32_16x16x32_bf16(kf[c][1], qa[1], sv[c], 0, 0, 0);
      }
      __builtin_amdgcn_s_setprio(0);
      #pragma unroll
      for (int c = 0; c < 2; ++c)
        if (ktu + c * 16 + 15 > rb0) {  // diagonal: mask key > q
          const int kb = ktu + c * 16 + quad * 4;
          #pragma unroll
          for (int r = 0; r < 4; ++r)
            if (kb + r > qrow) sv[c][r] = -1e30f;
        }
      float p[2][4];
      float ps = 0.f;
      #pragma unroll
      for (int c = 0; c < 2; ++c)
        #pragma unroll
        for (int r = 0; r < 4; ++r) {
          p[c][r] = __builtin_amdgcn_exp2f(sv[c][r]);   // raw v_exp_f32
          ps += p[c][r];
        }
      lsum += ps;

      union { unsigned u[4]; bf16x8 v8; } pf;   // slot j: key (j>=4?16:0)+quad*4+(j&3)
      pf.u[0] = pk2bf(p[0][0], p[0][1]);
      pf.u[1] = pk2bf(p[0][2], p[0][3]);
      pf.u[2] = pk2bf(p[1][0], p[1][1]);
      pf.u[3] = pk2bf(p[1][2], p[1][3]);
      __builtin_amdgcn_s_setprio(1);
      #pragma unroll
      for (int db = 0; db < 4; ++db)
        o[db] = __builtin_amdgcn_mfma_f32_16x16x32_bf16(vfr[db], pf.v8, o[db], 0, 0, 0);
      __builtin_amdgcn_s_setprio(0);
    }
  };

  int kt0;
  u2kt(u0, q0cur, kt0);
  resetacc();
  loadqa(q0cur);
  stage_u(u0);
  stage_u(u0 + 1);
  __syncthreads();   // own-wave vmcnt(0) drain + barrier: slots u0, u0+1 ready for ALL waves

  for (int u = u0; u < u1; u += 2) {
    if (u + 2 < u1) stage_u(u + 2);     // async prefetch into slots (u+2)&3, (u+3)&3
    if (u + 3 < u1) stage_u(u + 3);
    compute_u(u);
    compute_u(u + 1);
    __syncthreads();   // drains this wave's prefetch; all waves past reads of slots u,u+1
  }

  flush(q0cur);
  resetacc();
  if (q0cur == qoB * 128)      flush(qoA * 128);  // s=0: never reached tile A -> zero partials
  else if (u0 >= nB)           flush(qoB * 128);  // (unreachable for split-2; kept for safety)
}

// ---------------- combine partials: Y = sum(O_s)/sum(l_s), cast bf16 (split-2) ----------------
__global__ __launch_bounds__(256)
void combine_kernel(const bf16* __restrict__ PartO, const float* __restrict__ PartL,
                    bf16* __restrict__ Y) {
  const int e = blockIdx.x * 256 + threadIdx.x;   // 32*2048*16 threads (4 d each)
  const int dg = e & 15, row = e >> 4;            // row = bh*2048 + t
  const int bh = row >> 11, t = row & 2047;
  float ls = 0.f;
  float acc[4] = {0.f, 0.f, 0.f, 0.f};
  #pragma unroll
  for (int s = 0; s < 2; ++s) {
    ls += PartL[s * 65536 + row];
    const bf16x4 ov = *(const bf16x4*)(PartO + ((size_t)(s * 65536 + row)) * 64 + dg * 4);
    #pragma unroll
    for (int r = 0; r < 4; ++r) acc[r] += (float)ov[r];
  }
  const float inv = 1.0f / ls;
  const int b = bh >> 4, h = bh & 15;
  bf16x4 y;
  #pragma unroll
  for (int r = 0; r < 4; ++r) y[r] = f2bf(acc[r] * inv);
  *(bf16x4*)(Y + (size_t)(b * T_ + t) * C_ + h * 64 + dg * 4) = y;
}

// ---------------- launch ----------------
extern "C" void kernel_launch(void* const* d_in, const int* in_sizes, int n_in,
                              void* d_out, int out_size, void* d_ws, size_t ws_size,
                              hipStream_t stream) {
  const float* x      = (const float*)d_in[0];
  const float* W_attn = (const float*)d_in[1];
  const float* b_attn = (const float*)d_in[2];
  const float* W_l1   = (const float*)d_in[3];
  const float* b_l1   = (const float*)d_in[4];
  const float* W_l2   = (const float*)d_in[5];
  const float* b_l2   = (const float*)d_in[6];
  const float* W_proj = (const float*)d_in[7];
  const float* b_proj = (const float*)d_in[8];
  float* out = (float*)d_out;

  char* ws = (char*)d_ws;
  bf16* Xbf = (bf16*)(ws);                          //  8 MB  [M][C]
  bf16* WaT = (bf16*)(ws + ((size_t)8  << 20));     //  6 MB  [3C][C]
  bf16* WpT = (bf16*)(ws + ((size_t)14 << 20));     //  2 MB  [C][C]
  bf16* Qbf = (bf16*)(ws + ((size_t)16 << 20));     //  8 MB
  bf16* Kbf = (bf16*)(ws + ((size_t)24 << 20));     //  8 MB
  bf16* Vbf = (bf16*)(ws + ((size_t)32 << 20));     //  8 MB
  bf16* GVt = (bf16*)(ws + ((size_t)40 << 20));     //  8 MB  [b][h][j][t interleaved]
  bf16* Ybf = (bf16*)(ws + ((size_t)48 << 20));     //  8 MB
  bf16* PartO = (bf16*)(ws + ((size_t)56 << 20));   // 16 MB  [2][32*2048][64] bf16
  float* PartL = (float*)(ws + ((size_t)88 << 20)); // 0.5 MB [2][32*2048] fp32
  bf16* W1T = (bf16*)(ws + ((size_t)89 << 20));     //  8 KB  [j][d]
  bf16* W2T = (bf16*)(ws + ((size_t)89 << 20) + 8192);

  prep_kernel<<<4096 + 3072 + 1024 + 32, 256, 0, stream>>>(
      x, Xbf, W_attn, WaT, W_proj, WpT, W_l1, W_l2, W1T, W2T);

  gemm256_qkv<<<192, 512, 0, stream>>>(Xbf, WaT, b_attn, Qbf, Kbf, Vbf);

  gate_kernel<<<dim3(T_ / 128, B_ * H_), 256, 0, stream>>>(Vbf, W1T, b_l1, W2T, b_l2, GVt);

  flash_kernel<<<512, 512, 0, stream>>>(Qbf, Kbf, GVt, PartO, PartL);

  combine_kernel<<<32 * 2048 * 16 / 256, 256, 0, stream>>>(PartO, PartL, Ybf);

  gemm128_proj<<<256, 256, 0, stream>>>(Ybf, WpT, b_proj, out);

  (void)in_sizes; (void)n_in; (void)out_size; (void)ws_size;
}